// Round 4
// baseline (147.668 us; speedup 1.0000x reference)
//
#include <hip/hip_runtime.h>

// RuleGraphConvLayer: LDS-staged bf16 A-tile + MFMA, column-split waves,
// B-fragments hoisted into registers (12/wave, loaded before the barriers).
constexpr int kNodes = 262144;
constexpr int NC  = 103;   // feature columns
constexpr int F   = 81;    // used features
constexpr int OC  = 128;   // output channels
constexpr int NKS = 6;     // K steps: 6*32 = 192 >= 162
constexpr int KP  = 192;   // padded K
constexpr int LDK = 200;   // LDS row stride in bf16 (400 B -> 2-way banks: free)
constexpr int NPB = 64;    // nodes per block
constexpr int THREADS = 256;

typedef __attribute__((ext_vector_type(8))) short bf16x8;
typedef __attribute__((ext_vector_type(4))) float f32x4;

__device__ inline ushort f2bf(float f) {
  uint u = __float_as_uint(f);
  return (ushort)((u + 0x7fffu + ((u >> 16) & 1u)) >> 16);  // RNE
}

// Weight table in B-fragment order: wf[ks][ct][lane] = 8 bf16 (16B/lane).
// B[k][c]: k = ks*32 + (lane>>4)*8 + i, c = ct*16 + (lane&15).
__global__ __launch_bounds__(256)
void prep_w(const float* __restrict__ w_s, const float* __restrict__ w_n,
            ushort* __restrict__ wf) {
  int t = blockIdx.x * 256 + threadIdx.x;
  if (t >= NKS * 8 * 64) return;
  int l  = t & 63;
  int ct = (t >> 6) & 7;
  int ks = t >> 9;
  int c  = ct * 16 + (l & 15);
  int kb = ks * 32 + ((l >> 4) << 3);
  union { ushort u[8]; int4 v; } o;
  #pragma unroll
  for (int i = 0; i < 8; ++i) {
    int k = kb + i;
    float f = 0.f;
    if (k < F)          f = w_s[k * OC + c];
    else if (k < 2 * F) f = w_n[(k - F) * OC + c];
    o.u[i] = f2bf(f);
  }
  ((int4*)wf)[t] = o.v;
}

__global__ __launch_bounds__(THREADS, 4)
void rgc_fused(const float* __restrict__ feat, const ushort* __restrict__ wf,
               float* __restrict__ out) {
  __shared__ ushort a_bf[NPB * LDK];   // 25600 B
  __shared__ float  s_cs[NPB];
  __shared__ float  s_alive[NPB];
  __shared__ int    s_sel[NPB];

  const int  tid  = threadIdx.x;
  const int  w    = tid >> 6;
  const int  l    = tid & 63;
  const long base = (long)blockIdx.x * NPB;

  // ---- Hoisted B fragments: wave w owns column tiles ct=w and ct=w+4.
  // 12 independent 16B loads, in flight across phases 1-2. 12 KB/wave: L1-hot.
  const bf16x8* wfv = (const bf16x8*)wf;
  bf16x8 bA[NKS], bB[NKS];
  #pragma unroll
  for (int ks = 0; ks < NKS; ++ks) {
    bA[ks] = wfv[(ks * 8 + w)     * 64 + l];
    bB[ks] = wfv[(ks * 8 + w + 4) * 64 + l];
  }

  // ---- Phase 1: per-node neighbor select + 1/d^2 scale
  if (tid < NPB) {
    const float* row = feat + (base + tid) * NC;
    int i0 = (int)row[F];
    int i1 = (int)row[F + 1];
    int sel = (i1 != 0) ? i1 : i0;
    float alive = (i1 != 0 || i0 != 0) ? 1.f : 0.f;
    const float* nrow = feat + (long)sel * NC;
    float dx = row[0] - nrow[0];
    float dy = row[1] - nrow[1];
    float dz = row[2] - nrow[2];
    float d2 = dx * dx + dy * dy + dz * dz;
    s_sel[tid]   = sel;
    s_alive[tid] = alive;
    s_cs[tid]    = alive * ((d2 > 0.f) ? (1.f / d2) : 10000.f);
  }
  __syncthreads();

  // ---- Phase 2: build 64x192 bf16 A-tile, 4 bf16/thread/iter (12 iters).
  #pragma unroll 2
  for (int e = tid; e < NPB * (KP / 4); e += THREADS) {
    int n  = e / (KP / 4);            // KP/4 = 48 threads per node row
    int kp = (e - n * (KP / 4)) * 4;
    const float* srow = feat + (base + n) * NC;
    int   sel   = s_sel[n];
    float cs    = s_cs[n];
    float alive = s_alive[n];
    const float* nrow = feat + (long)sel * NC;
    ushort u[4];
    #pragma unroll
    for (int j = 0; j < 4; ++j) {
      int k = kp + j;
      float x;
      if (k < F) {
        x = srow[k] * alive;
      } else if (k < 2 * F) {
        int kk = k - F;
        float nv = nrow[kk];
        float sv = (kk < 3) ? 0.f : srow[kk];
        x = (nv + sv) * cs;
      } else {
        x = 0.f;
      }
      u[j] = f2bf(x);
    }
    uint2 pack;
    pack.x = (uint)u[0] | ((uint)u[1] << 16);
    pack.y = (uint)u[2] | ((uint)u[3] << 16);
    *(uint2*)(&a_bf[n * LDK + kp]) = pack;
  }
  __syncthreads();

  // ---- Phase 3: each wave does all 4 row-tiles for its 2 column tiles.
  const int lrow = l & 15;
  const int lk   = (l >> 4) << 3;
  const int col  = l & 15;
  const int rsub = (l >> 4) << 2;

  #pragma unroll
  for (int t = 0; t < 4; ++t) {
    const ushort* arow = a_bf + (t * 16 + lrow) * LDK + lk;
    bf16x8 af[NKS];
    #pragma unroll
    for (int ks = 0; ks < NKS; ++ks) af[ks] = *(const bf16x8*)(arow + ks * 32);

    f32x4 acc0 = (f32x4)(0.f), acc1 = (f32x4)(0.f);
    #pragma unroll
    for (int ks = 0; ks < NKS; ++ks) {
      acc0 = __builtin_amdgcn_mfma_f32_16x16x32_bf16(af[ks], bA[ks], acc0, 0, 0, 0);
      acc1 = __builtin_amdgcn_mfma_f32_16x16x32_bf16(af[ks], bB[ks], acc1, 0, 0, 0);
    }

    // C/D: col = lane&15, row = (lane>>4)*4 + reg  [learn_hip m89/m91]
    const long orow = base + t * 16 + rsub;
    #pragma unroll
    for (int r = 0; r < 4; ++r) {
      out[(orow + r) * OC + w * 16       + col] = acc0[r];
      out[(orow + r) * OC + (w + 4) * 16 + col] = acc1[r];
    }
  }
}

extern "C" void kernel_launch(void* const* d_in, const int* in_sizes, int n_in,
                              void* d_out, int out_size, void* d_ws, size_t ws_size,
                              hipStream_t stream) {
  const float* feat = (const float*)d_in[0];
  const float* w_s  = (const float*)d_in[1];
  const float* w_n  = (const float*)d_in[2];
  float* outp = (float*)d_out;
  ushort* wf = (ushort*)d_ws;  // 6*8*64*8 bf16 = 49152 bytes

  prep_w<<<dim3((NKS * 8 * 64 + 255) / 256), 256, 0, stream>>>(w_s, w_n, wf);
  rgc_fused<<<dim3(kNodes / NPB), THREADS, 0, stream>>>(feat, wf, outp);
}

// Round 5
// 86.683 us; speedup vs baseline: 1.7035x; 1.7035x over previous
//
#include <hip/hip_runtime.h>

// RuleGraphConvLayer, flat zero-LDS MFMA with K-slot remap.
// K = 192 slots: [0..80] self, [81..95] B-zeroed pad, [96..176] comb, [177..191] pad.
// Comb slot kk = slot-96 uses the SAME dword offsets as self slots -> each lane
// loads only 3 self chunks + 3 nei chunks (8 dwords each) + preamble.
// Garbage in pad slots (incl idx cols 81,82) is finite and hits zero B rows.
constexpr int kNodes = 262144;
constexpr int NC  = 103;   // feature columns
constexpr int F   = 81;    // used features
constexpr int OC  = 128;   // output channels
constexpr int NKS = 6;     // 6*32 = 192 K slots
constexpr int THREADS = 256;

typedef __attribute__((ext_vector_type(8))) short bf16x8;
typedef __attribute__((ext_vector_type(4))) float f32x4;
typedef float f32x4a __attribute__((ext_vector_type(4))) __attribute__((aligned(4)));

__device__ inline ushort f2bf(float f) {
  uint u = __float_as_uint(f);
  return (ushort)((u + 0x7fffu + ((u >> 16) & 1u)) >> 16);  // RNE
}

// B table in fragment order: wf[ks][ct][lane] = 8 bf16.
// B[k][c]: k = ks*32 + (lane>>4)*8 + i, c = ct*16 + (lane&15).
// Logical rows: k<81 -> w_s[k]; 96<=k<177 -> w_n[k-96]; else 0.
__global__ __launch_bounds__(256)
void prep_w(const float* __restrict__ w_s, const float* __restrict__ w_n,
            ushort* __restrict__ wf) {
  int t = blockIdx.x * 256 + threadIdx.x;
  if (t >= NKS * 8 * 64) return;
  int l  = t & 63;
  int ct = (t >> 6) & 7;
  int ks = t >> 9;
  int c  = ct * 16 + (l & 15);
  int kb = ks * 32 + ((l >> 4) << 3);
  union { ushort u[8]; int4 v; } o;
  #pragma unroll
  for (int i = 0; i < 8; ++i) {
    int k = kb + i;
    float f = 0.f;
    if (k < F)                     f = w_s[k * OC + c];
    else if (k >= 96 && k < 96+F)  f = w_n[(k - 96) * OC + c];
    o.u[i] = f2bf(f);
  }
  ((int4*)wf)[t] = o.v;
}

__global__ __launch_bounds__(THREADS, 4)
void rgc_flat(const float* __restrict__ feat, const ushort* __restrict__ wf,
              float* __restrict__ out) {
  const int tid  = threadIdx.x;
  const int l    = tid & 63;
  const int q    = l >> 4;       // lane quadrant: k sub-offset q*8
  const int lrow = l & 15;       // A-row within 16x16 tile
  const long tbase = (long)(blockIdx.x * 4 + (tid >> 6)) * 16;
  const float* srow = feat + (tbase + lrow) * NC;

  // ---- Preamble: idx first (nei address dependency), then coords.
  f32x4a pidx = *(const f32x4a*)(srow + 80);     // {f80, idx0, idx1, f83}
  int i0 = (int)pidx.y;
  int i1 = (int)pidx.z;
  int sel = (i1 != 0) ? i1 : i0;
  float alive = (i1 != 0 || i0 != 0) ? 1.f : 0.f;
  const float* nrow = feat + (long)sel * NC;
  f32x4a scd = *(const f32x4a*)(srow);
  f32x4a ncd = *(const f32x4a*)(nrow);
  float dx = scd.x - ncd.x, dy = scd.y - ncd.y, dz = scd.z - ncd.z;
  float d2 = dx * dx + dy * dy + dz * dz;
  float inv = (d2 > 0.f) ? (1.f / d2) : 10000.f;
  float cs  = alive * inv;

  // ---- Load all chunks (independent; in flight together).
  // Chunk c: dwords [32c + 8q, +8). Max offset 88+7 = 95 < 103: in bounds.
  f32x4a s8[3][2], n8[3][2];
  #pragma unroll
  for (int c = 0; c < 3; ++c) {
    const int off = c * 32 + q * 8;
    s8[c][0] = *(const f32x4a*)(srow + off);
    s8[c][1] = *(const f32x4a*)(srow + off + 4);
    n8[c][0] = *(const f32x4a*)(nrow + off);
    n8[c][1] = *(const f32x4a*)(nrow + off + 4);
  }

  // ---- Build A fragments. Pad slots carry finite garbage x zero B rows.
  bf16x8 afS[3], afC[3];
  #pragma unroll
  for (int c = 0; c < 3; ++c) {
    #pragma unroll
    for (int h = 0; h < 2; ++h) {
      #pragma unroll
      for (int i = 0; i < 4; ++i) {
        float sv = s8[c][h][i];
        float nv = n8[c][h][i];
        afS[c][h * 4 + i] = (short)f2bf(sv * alive);
        // coord-exclusion: comb slots kk<3 use nei only (chunk c==0,q==0,i<3)
        float se = sv;
        if (c == 0 && h == 0 && i < 3) se = (q == 0) ? 0.f : sv;
        afC[c][h * 4 + i] = (short)f2bf((nv + se) * cs);
      }
    }
  }

  // ---- MFMA: 6 ks x 8 ct, B frags from global (L1/L2-hot table).
  const bf16x8* wfv = (const bf16x8*)wf;
  f32x4 acc[8];
  #pragma unroll
  for (int i = 0; i < 8; ++i) acc[i] = (f32x4)(0.f);

  #pragma unroll
  for (int ks = 0; ks < NKS; ++ks) {
    bf16x8 af = (ks < 3) ? afS[ks] : afC[ks - 3];
    #pragma unroll
    for (int ct = 0; ct < 8; ++ct) {
      bf16x8 bfr = wfv[(ks * 8 + ct) * 64 + l];
      acc[ct] = __builtin_amdgcn_mfma_f32_16x16x32_bf16(af, bfr, acc[ct], 0, 0, 0);
    }
  }

  // ---- Store. C/D: col = lane&15, row = (lane>>4)*4 + reg  [m89/m91]
  const long orow = tbase + q * 4;
  const int  col  = l & 15;
  #pragma unroll
  for (int ct = 0; ct < 8; ++ct) {
    #pragma unroll
    for (int r = 0; r < 4; ++r) {
      out[(orow + r) * OC + ct * 16 + col] = acc[ct][r];
    }
  }
}

extern "C" void kernel_launch(void* const* d_in, const int* in_sizes, int n_in,
                              void* d_out, int out_size, void* d_ws, size_t ws_size,
                              hipStream_t stream) {
  const float* feat = (const float*)d_in[0];
  const float* w_s  = (const float*)d_in[1];
  const float* w_n  = (const float*)d_in[2];
  float* outp = (float*)d_out;
  ushort* wf = (ushort*)d_ws;  // 6*8*64*8 bf16 = 49152 bytes

  prep_w<<<dim3((NKS * 8 * 64 + 255) / 256), 256, 0, stream>>>(w_s, w_n, wf);
  rgc_flat<<<dim3(kNodes / 64), THREADS, 0, stream>>>(feat, wf, outp);
}

// Round 6
// 79.110 us; speedup vs baseline: 1.8666x; 1.0957x over previous
//
#include <hip/hip_runtime.h>
#include <hip/hip_bf16.h>

// RuleGraphConvLayer, flat zero-LDS MFMA with K-slot remap + forced load MLP.
// K = 192 slots: [0..80] self, [81..95] B-zeroed pad, [96..176] comb, [177..191] pad.
// Comb slot kk = slot-96 shares dword offsets with self slots -> lane loads
// 24 self dwords + 24 nei dwords, all issued in two straight-line bursts.
constexpr int kNodes = 262144;
constexpr int NC  = 103;   // feature columns
constexpr int F   = 81;    // used features
constexpr int OC  = 128;   // output channels
constexpr int NKS = 6;     // 6*32 = 192 K slots
constexpr int THREADS = 256;

typedef __attribute__((ext_vector_type(8))) short bf16x8;
typedef __attribute__((ext_vector_type(4))) float f32x4;

__device__ inline ushort f2bf(float f) {
  uint u = __float_as_uint(f);
  return (ushort)((u + 0x7fffu + ((u >> 16) & 1u)) >> 16);  // RNE
}

// B table in fragment order: wf[ks][ct][lane] = 8 bf16.
// B[k][c]: k = ks*32 + (lane>>4)*8 + i, c = ct*16 + (lane&15).
// Rows: k<81 -> w_s[k]; 96<=k<177 -> w_n[k-96]; else 0.
__global__ __launch_bounds__(256)
void prep_w(const float* __restrict__ w_s, const float* __restrict__ w_n,
            ushort* __restrict__ wf) {
  int t = blockIdx.x * 256 + threadIdx.x;
  if (t >= NKS * 8 * 64) return;
  int l  = t & 63;
  int ct = (t >> 6) & 7;
  int ks = t >> 9;
  int c  = ct * 16 + (l & 15);
  int kb = ks * 32 + ((l >> 4) << 3);
  union { ushort u[8]; int4 v; } o;
  #pragma unroll
  for (int i = 0; i < 8; ++i) {
    int k = kb + i;
    float f = 0.f;
    if (k < F)                      f = w_s[k * OC + c];
    else if (k >= 96 && k < 96 + F) f = w_n[(k - 96) * OC + c];
    o.u[i] = f2bf(f);
  }
  ((int4*)wf)[t] = o.v;
}

__device__ inline short bfc(float x) {
  return (short)__bfloat16_as_ushort(__float2bfloat16(x));
}

__global__ __launch_bounds__(THREADS, 2)
void rgc_flat(const float* __restrict__ feat, const ushort* __restrict__ wf,
              float* __restrict__ out) {
  const int tid  = threadIdx.x;
  const int l    = tid & 63;
  const int q    = l >> 4;       // k sub-offset q*8
  const int lrow = l & 15;       // A-row within 16x16 tile
  const int off0 = q * 8;
  const long tbase = (long)(blockIdx.x * 4 + (tid >> 6)) * 16;
  const float* srow = feat + (tbase + lrow) * NC;
  const bf16x8* wfv = (const bf16x8*)wf;

  // ---- Burst 1: ALL self-row loads + idx + first B stage (independent).
  float pidx0 = srow[F];
  float pidx1 = srow[F + 1];
  float sc0 = srow[0], sc1 = srow[1], sc2 = srow[2];
  float s[24];
  #pragma unroll
  for (int c = 0; c < 3; ++c)
    #pragma unroll
    for (int i = 0; i < 8; ++i)
      s[c * 8 + i] = srow[c * 32 + off0 + i];

  bf16x8 bcur[8], bnxt[8];
  #pragma unroll
  for (int ct = 0; ct < 8; ++ct) bcur[ct] = wfv[ct * 64 + l];

  // ---- Resolve neighbor, then Burst 2: ALL nei-row loads.
  int i0 = (int)pidx0, i1 = (int)pidx1;
  int sel = (i1 != 0) ? i1 : i0;
  float alive = (i1 != 0 || i0 != 0) ? 1.f : 0.f;
  const float* nrow = feat + (long)sel * NC;
  float nc0 = nrow[0], nc1 = nrow[1], nc2 = nrow[2];
  float n[24];
  #pragma unroll
  for (int c = 0; c < 3; ++c)
    #pragma unroll
    for (int i = 0; i < 8; ++i)
      n[c * 8 + i] = nrow[c * 32 + off0 + i];

  float dx = sc0 - nc0, dy = sc1 - nc1, dz = sc2 - nc2;
  float d2 = dx * dx + dy * dy + dz * dz;
  float cs = alive * ((d2 > 0.f) ? (1.f / d2) : 10000.f);

  // ---- Build A fragments (pad slots carry finite garbage x zero B rows).
  bf16x8 afS[3], afC[3];
  #pragma unroll
  for (int c = 0; c < 3; ++c) {
    #pragma unroll
    for (int i = 0; i < 8; ++i) {
      float sv = s[c * 8 + i];
      float nv = n[c * 8 + i];
      afS[c][i] = bfc(sv * alive);
      float se = sv;
      if (c == 0 && i < 3) se = (q == 0) ? 0.f : sv;  // comb kk<3: nei coords only
      afC[c][i] = bfc((nv + se) * cs);
    }
  }

  // ---- MFMA: 6 ks x 8 ct, B stream double-buffered (8 loads in flight).
  f32x4 acc[8];
  #pragma unroll
  for (int i = 0; i < 8; ++i) acc[i] = (f32x4)(0.f);

  #pragma unroll
  for (int ks = 0; ks < NKS; ++ks) {
    if (ks + 1 < NKS) {
      #pragma unroll
      for (int ct = 0; ct < 8; ++ct) bnxt[ct] = wfv[((ks + 1) * 8 + ct) * 64 + l];
    }
    bf16x8 af = (ks < 3) ? afS[ks] : afC[ks - 3];
    #pragma unroll
    for (int ct = 0; ct < 8; ++ct)
      acc[ct] = __builtin_amdgcn_mfma_f32_16x16x32_bf16(af, bcur[ct], acc[ct], 0, 0, 0);
    #pragma unroll
    for (int ct = 0; ct < 8; ++ct) bcur[ct] = bnxt[ct];
  }

  // ---- Store. C/D: col = lane&15, row = (lane>>4)*4 + reg  [m89/m91]
  const long orow = tbase + q * 4;
  const int  col  = l & 15;
  #pragma unroll
  for (int ct = 0; ct < 8; ++ct) {
    #pragma unroll
    for (int r = 0; r < 4; ++r) {
      out[(orow + r) * OC + ct * 16 + col] = acc[ct][r];
    }
  }
}

extern "C" void kernel_launch(void* const* d_in, const int* in_sizes, int n_in,
                              void* d_out, int out_size, void* d_ws, size_t ws_size,
                              hipStream_t stream) {
  const float* feat = (const float*)d_in[0];
  const float* w_s  = (const float*)d_in[1];
  const float* w_n  = (const float*)d_in[2];
  float* outp = (float*)d_out;
  ushort* wf = (ushort*)d_ws;  // 6*8*64*8 bf16 = 49152 bytes

  prep_w<<<dim3((NKS * 8 * 64 + 255) / 256), 256, 0, stream>>>(w_s, w_n, wf);
  rgc_flat<<<dim3(kNodes / 64), THREADS, 0, stream>>>(feat, wf, outp);
}

// Round 7
// 68.523 us; speedup vs baseline: 2.1550x; 1.1545x over previous
//
#include <hip/hip_runtime.h>
#include <hip/hip_bf16.h>

// RuleGraphConvLayer, flat zero-LDS MFMA. K-slot remap + asm-pinned load bursts
// + 32 nodes per wave (two 16-row tiles sharing the B stream).
// K = 192 slots: [0..80] self, [81..95] pad(B=0), [96..176] comb, [177..191] pad.
constexpr int kNodes = 262144;
constexpr int NC  = 103;   // feature columns
constexpr int F   = 81;    // used features
constexpr int OC  = 128;   // output channels
constexpr int NKS = 6;     // 6*32 = 192 K slots
constexpr int THREADS = 256;

typedef __attribute__((ext_vector_type(8))) short bf16x8;
typedef __attribute__((ext_vector_type(4))) float f32x4;
typedef __attribute__((ext_vector_type(8))) float f32x8;

__device__ inline ushort f2bf(float f) {
  uint u = __float_as_uint(f);
  return (ushort)((u + 0x7fffu + ((u >> 16) & 1u)) >> 16);  // RNE
}

// B table in fragment order: wf[ks][ct][lane] = 8 bf16.
// B[k][c]: k = ks*32 + (lane>>4)*8 + i, c = ct*16 + (lane&15).
// Rows: k<81 -> w_s[k]; 96<=k<177 -> w_n[k-96]; else 0.
__global__ __launch_bounds__(256)
void prep_w(const float* __restrict__ w_s, const float* __restrict__ w_n,
            ushort* __restrict__ wf) {
  int t = blockIdx.x * 256 + threadIdx.x;
  if (t >= NKS * 8 * 64) return;
  int l  = t & 63;
  int ct = (t >> 6) & 7;
  int ks = t >> 9;
  int c  = ct * 16 + (l & 15);
  int kb = ks * 32 + ((l >> 4) << 3);
  union { ushort u[8]; int4 v; } o;
  #pragma unroll
  for (int i = 0; i < 8; ++i) {
    int k = kb + i;
    float f = 0.f;
    if (k < F)                      f = w_s[k * OC + c];
    else if (k >= 96 && k < 96 + F) f = w_n[(k - 96) * OC + c];
    o.u[i] = f2bf(f);
  }
  ((int4*)wf)[t] = o.v;
}

__device__ inline short bfc(float x) {
  return (short)__bfloat16_as_ushort(__float2bfloat16(x));
}

#define LOAD8(dst, p, base)                 \
  {                                         \
    _Pragma("unroll")                       \
    for (int _i = 0; _i < 8; ++_i) (dst)[_i] = (p)[(base) + _i]; \
  }

__global__ __launch_bounds__(THREADS)
void rgc_flat32(const float* __restrict__ feat, const ushort* __restrict__ wf,
                float* __restrict__ out) {
  const int tid  = threadIdx.x;
  const int l    = tid & 63;
  const int q    = l >> 4;       // k sub-offset q*8
  const int lrow = l & 15;
  const int off0 = q * 8;
  const long wbase = (long)(blockIdx.x * 4 + (tid >> 6)) * 32;  // 32 nodes/wave
  const float* srowA = feat + (wbase + lrow) * NC;
  const float* srowB = feat + (wbase + 16 + lrow) * NC;
  const bf16x8* wfv = (const bf16x8*)wf;

  // ---- Burst 1: all self dwords for both tiles + idx + coords.
  f32x8 vA0, vA1, vA2, vB0, vB1, vB2;
  LOAD8(vA0, srowA, off0); LOAD8(vA1, srowA, 32 + off0); LOAD8(vA2, srowA, 64 + off0);
  LOAD8(vB0, srowB, off0); LOAD8(vB1, srowB, 32 + off0); LOAD8(vB2, srowB, 64 + off0);
  float iA0 = srowA[F], iA1 = srowA[F + 1];
  float iB0 = srowB[F], iB1 = srowB[F + 1];
  float cA0 = srowA[0], cA1 = srowA[1], cA2 = srowA[2];
  float cB0 = srowB[0], cB1 = srowB[1], cB2 = srowB[2];
  asm volatile("" :: "v"(vA0), "v"(vA1), "v"(vA2), "v"(vB0), "v"(vB1), "v"(vB2));

  // ---- Resolve neighbors; Burst 2: all nei dwords for both tiles.
  int selA; float aliveA;
  { int i0 = (int)iA0, i1 = (int)iA1;
    selA = (i1 != 0) ? i1 : i0; aliveA = (i1 != 0 || i0 != 0) ? 1.f : 0.f; }
  int selB; float aliveB;
  { int i0 = (int)iB0, i1 = (int)iB1;
    selB = (i1 != 0) ? i1 : i0; aliveB = (i1 != 0 || i0 != 0) ? 1.f : 0.f; }
  const float* nrowA = feat + (long)selA * NC;
  const float* nrowB = feat + (long)selB * NC;

  f32x8 wA0, wA1, wA2, wB0, wB1, wB2;
  LOAD8(wA0, nrowA, off0); LOAD8(wA1, nrowA, 32 + off0); LOAD8(wA2, nrowA, 64 + off0);
  LOAD8(wB0, nrowB, off0); LOAD8(wB1, nrowB, 32 + off0); LOAD8(wB2, nrowB, 64 + off0);
  float nA0 = nrowA[0], nA1 = nrowA[1], nA2 = nrowA[2];
  float nB0 = nrowB[0], nB1 = nrowB[1], nB2 = nrowB[2];
  asm volatile("" :: "v"(wA0), "v"(wA1), "v"(wA2), "v"(wB0), "v"(wB1), "v"(wB2));

  float dxA = cA0 - nA0, dyA = cA1 - nA1, dzA = cA2 - nA2;
  float d2A = dxA * dxA + dyA * dyA + dzA * dzA;
  float csA = aliveA * ((d2A > 0.f) ? (1.f / d2A) : 10000.f);
  float dxB = cB0 - nB0, dyB = cB1 - nB1, dzB = cB2 - nB2;
  float d2B = dxB * dxB + dyB * dyB + dzB * dzB;
  float csB = aliveB * ((d2B > 0.f) ? (1.f / d2B) : 10000.f);

  // ---- Build A fragments (pad slots: finite garbage x zero B rows).
  bf16x8 fSA[3], fCA[3], fSB[3], fCB[3];
  {
    const f32x8 sA[3] = {vA0, vA1, vA2}, sB[3] = {vB0, vB1, vB2};
    const f32x8 nA[3] = {wA0, wA1, wA2}, nB[3] = {wB0, wB1, wB2};
    #pragma unroll
    for (int c = 0; c < 3; ++c) {
      #pragma unroll
      for (int i = 0; i < 8; ++i) {
        float svA = sA[c][i], nvA = nA[c][i];
        float svB = sB[c][i], nvB = nB[c][i];
        fSA[c][i] = bfc(svA * aliveA);
        fSB[c][i] = bfc(svB * aliveB);
        float seA = svA, seB = svB;
        if (c == 0 && i < 3 && q == 0) { seA = 0.f; seB = 0.f; }  // comb kk<3: nei only
        fCA[c][i] = bfc((nvA + seA) * csA);
        fCB[c][i] = bfc((nvB + seB) * csB);
      }
    }
  }

  // ---- MFMA in two ct-halves; B double-buffered (4 frags in flight).
  const int col = l & 15;
  #pragma unroll
  for (int h = 0; h < 2; ++h) {
    f32x4 accA[4], accB[4];
    #pragma unroll
    for (int j = 0; j < 4; ++j) { accA[j] = (f32x4)(0.f); accB[j] = (f32x4)(0.f); }

    bf16x8 bc[4], bn[4];
    #pragma unroll
    for (int j = 0; j < 4; ++j) bc[j] = wfv[(h * 4 + j) * 64 + l];

    #pragma unroll
    for (int ks = 0; ks < NKS; ++ks) {
      if (ks + 1 < NKS) {
        #pragma unroll
        for (int j = 0; j < 4; ++j) bn[j] = wfv[((ks + 1) * 8 + h * 4 + j) * 64 + l];
      }
      bf16x8 afA = (ks < 3) ? fSA[ks] : fCA[ks - 3];
      bf16x8 afB = (ks < 3) ? fSB[ks] : fCB[ks - 3];
      #pragma unroll
      for (int j = 0; j < 4; ++j) {
        accA[j] = __builtin_amdgcn_mfma_f32_16x16x32_bf16(afA, bc[j], accA[j], 0, 0, 0);
        accB[j] = __builtin_amdgcn_mfma_f32_16x16x32_bf16(afB, bc[j], accB[j], 0, 0, 0);
      }
      #pragma unroll
      for (int j = 0; j < 4; ++j) bc[j] = bn[j];
    }

    // C/D: col = lane&15, row = (lane>>4)*4 + reg  [m89/m91]
    #pragma unroll
    for (int j = 0; j < 4; ++j) {
      const int ct = h * 4 + j;
      #pragma unroll
      for (int r = 0; r < 4; ++r) {
        out[(wbase + q * 4 + r) * OC + ct * 16 + col]      = accA[j][r];
        out[(wbase + 16 + q * 4 + r) * OC + ct * 16 + col] = accB[j][r];
      }
    }
  }
}

extern "C" void kernel_launch(void* const* d_in, const int* in_sizes, int n_in,
                              void* d_out, int out_size, void* d_ws, size_t ws_size,
                              hipStream_t stream) {
  const float* feat = (const float*)d_in[0];
  const float* w_s  = (const float*)d_in[1];
  const float* w_n  = (const float*)d_in[2];
  float* outp = (float*)d_out;
  ushort* wf = (ushort*)d_ws;  // 6*8*64*8 bf16 = 49152 bytes

  prep_w<<<dim3((NKS * 8 * 64 + 255) / 256), 256, 0, stream>>>(w_s, w_n, wf);
  rgc_flat32<<<dim3(kNodes / 128), THREADS, 0, stream>>>(feat, wf, outp);
}

// Round 8
// 67.915 us; speedup vs baseline: 2.1743x; 1.0090x over previous
//
#include <hip/hip_runtime.h>
#include <hip/hip_bf16.h>

// RuleGraphConvLayer R8: fully-coalesced staging + col-split MFMA.
// K = 192 slots: [0..80] self, [81..95] pad(B=0), [96..176] comb, [177..191] pad.
// LDS: raw f32 self rows (stride 103, contiguous copy) + gathered nei rows
// (stride 100). Wave w computes column tiles {w, w+4} for all 64 nodes;
// its 12 B-fragments live in VGPRs, loaded once. Stores hit full 64B lines.
constexpr int kNodes = 262144;
constexpr int NC  = 103;   // feature columns
constexpr int F   = 81;    // used features
constexpr int OC  = 128;   // output channels
constexpr int NKS = 6;     // 6*32 = 192 K slots
constexpr int NPB = 64;    // nodes per block
constexpr int THREADS = 256;
constexpr int NEI_STRIDE = 100;  // 96 used + 4 pad (2-way banks, 16B align)
constexpr int GW = 96;           // dwords gathered per nei row

typedef __attribute__((ext_vector_type(8))) short bf16x8;
typedef __attribute__((ext_vector_type(4))) float f32x4;

__device__ inline ushort f2bf(float f) {
  uint u = __float_as_uint(f);
  return (ushort)((u + 0x7fffu + ((u >> 16) & 1u)) >> 16);  // RNE
}

__device__ inline short bfc(float x) {
  return (short)__bfloat16_as_ushort(__float2bfloat16(x));
}

// B table in fragment order: wf[ks][ct][lane] = 8 bf16.
// B[k][c]: k = ks*32 + (lane>>4)*8 + i, c = ct*16 + (lane&15).
// Rows: k<81 -> w_s[k]; 96<=k<177 -> w_n[k-96]; else 0.
__global__ __launch_bounds__(256)
void prep_w(const float* __restrict__ w_s, const float* __restrict__ w_n,
            ushort* __restrict__ wf) {
  int t = blockIdx.x * 256 + threadIdx.x;
  if (t >= NKS * 8 * 64) return;
  int l  = t & 63;
  int ct = (t >> 6) & 7;
  int ks = t >> 9;
  int c  = ct * 16 + (l & 15);
  int kb = ks * 32 + ((l >> 4) << 3);
  union { ushort u[8]; int4 v; } o;
  #pragma unroll
  for (int i = 0; i < 8; ++i) {
    int k = kb + i;
    float f = 0.f;
    if (k < F)                      f = w_s[k * OC + c];
    else if (k >= 96 && k < 96 + F) f = w_n[(k - 96) * OC + c];
    o.u[i] = f2bf(f);
  }
  ((int4*)wf)[t] = o.v;
}

__global__ __launch_bounds__(THREADS)
void rgc_v8(const float* __restrict__ feat, const ushort* __restrict__ wf,
            float* __restrict__ out) {
  __shared__ float lds_self[NPB * NC];          // 26368 B (raw rows, stride 103)
  __shared__ float lds_nei[NPB * NEI_STRIDE];   // 25600 B (stride 100)
  __shared__ int   s_sel[NPB];
  __shared__ float s_alive[NPB];
  __shared__ float s_cs[NPB];

  const int tid = threadIdx.x;
  const int w   = tid >> 6;
  const int l   = tid & 63;
  const long base = (long)blockIdx.x * NPB;
  const float* fbase = feat + base * NC;

  // ---- Hoisted B fragments: wave w owns ct = w and w+4 (12 x 16B, once).
  const bf16x8* wfv = (const bf16x8*)wf;
  bf16x8 bA[NKS], bB[NKS];
  #pragma unroll
  for (int ks = 0; ks < NKS; ++ks) {
    bA[ks] = wfv[(ks * 8 + w)     * 64 + l];
    bB[ks] = wfv[(ks * 8 + w + 4) * 64 + l];
  }

  // ---- Phase 1: raw self-row copy, fully coalesced float4 (6592 dwords).
  {
    const float4* src = (const float4*)fbase;   // 16B-aligned: 64*103*4 % 16 == 0
    float4* dst = (float4*)lds_self;
    #pragma unroll
    for (int i = tid; i < NPB * NC / 4; i += THREADS) dst[i] = src[i];
  }
  __syncthreads();

  // ---- Phase 2: neighbor select per node (from LDS).
  if (tid < NPB) {
    int n = tid;
    int i0 = (int)lds_self[n * NC + F];
    int i1 = (int)lds_self[n * NC + F + 1];
    s_sel[n]   = (i1 != 0) ? i1 : i0;
    s_alive[n] = (i1 != 0 || i0 != 0) ? 1.f : 0.f;
  }
  __syncthreads();

  // ---- Phase 3: nei gather, lane-stride-4B (~6 lines/instr), 24 iters.
  #pragma unroll
  for (int j = 0; j < 24; ++j) {
    int v   = tid + j * THREADS;      // 0..6143
    int row = v / GW;
    int col = v - row * GW;
    lds_nei[row * NEI_STRIDE + col] = feat[(long)s_sel[row] * NC + col];
  }
  __syncthreads();

  // ---- Phase 4: 1/d^2 scale per node.
  if (tid < NPB) {
    int n = tid;
    float dx = lds_self[n * NC + 0] - lds_nei[n * NEI_STRIDE + 0];
    float dy = lds_self[n * NC + 1] - lds_nei[n * NEI_STRIDE + 1];
    float dz = lds_self[n * NC + 2] - lds_nei[n * NEI_STRIDE + 2];
    float d2 = dx * dx + dy * dy + dz * dz;
    s_cs[n] = s_alive[n] * ((d2 > 0.f) ? (1.f / d2) : 10000.f);
  }
  __syncthreads();

  // ---- Phase 5: per wave, 4 node-tiles x 2 column tiles. A from LDS,
  // B from VGPRs. Pad slots carry finite garbage x zero B rows.
  const int q    = l >> 4;
  const int lrow = l & 15;
  const int off0 = q * 8;
  const int col  = l & 15;

  #pragma unroll
  for (int nt = 0; nt < 4; ++nt) {
    const int n = nt * 16 + lrow;
    const float* sp = lds_self + n * NC;
    const float* np = lds_nei + n * NEI_STRIDE;
    const float alive = s_alive[n];
    const float cs    = s_cs[n];

    bf16x8 afS[3], afC[3];
    #pragma unroll
    for (int c = 0; c < 3; ++c) {
      #pragma unroll
      for (int i = 0; i < 8; ++i) {
        float sv = sp[c * 32 + off0 + i];
        float nv = np[c * 32 + off0 + i];
        afS[c][i] = bfc(sv * alive);
        float se = sv;
        if (c == 0 && i < 3 && q == 0) se = 0.f;  // comb kk<3: nei coords only
        afC[c][i] = bfc((nv + se) * cs);
      }
    }

    f32x4 a0 = (f32x4)(0.f), a1 = (f32x4)(0.f);
    #pragma unroll
    for (int ks = 0; ks < NKS; ++ks) {
      bf16x8 af = (ks < 3) ? afS[ks] : afC[ks - 3];
      a0 = __builtin_amdgcn_mfma_f32_16x16x32_bf16(af, bA[ks], a0, 0, 0, 0);
      a1 = __builtin_amdgcn_mfma_f32_16x16x32_bf16(af, bB[ks], a1, 0, 0, 0);
    }

    // C/D: col = lane&15, row = (lane>>4)*4 + reg  [m89/m91]
    // Each store instr: 4 rows x one full 64B line -> perfect write-combining.
    const long orow = base + nt * 16 + q * 4;
    #pragma unroll
    for (int r = 0; r < 4; ++r) {
      out[(orow + r) * OC + w * 16       + col] = a0[r];
      out[(orow + r) * OC + (w + 4) * 16 + col] = a1[r];
    }
  }
}

extern "C" void kernel_launch(void* const* d_in, const int* in_sizes, int n_in,
                              void* d_out, int out_size, void* d_ws, size_t ws_size,
                              hipStream_t stream) {
  const float* feat = (const float*)d_in[0];
  const float* w_s  = (const float*)d_in[1];
  const float* w_n  = (const float*)d_in[2];
  float* outp = (float*)d_out;
  ushort* wf = (ushort*)d_ws;  // 6*8*64*8 bf16 = 49152 bytes

  prep_w<<<dim3((NKS * 8 * 64 + 255) / 256), 256, 0, stream>>>(w_s, w_n, wf);
  rgc_v8<<<dim3(kNodes / NPB), THREADS, 0, stream>>>(feat, wf, outp);
}